// Round 1
// baseline (6641.788 us; speedup 1.0000x reference)
//
#include <hip/hip_runtime.h>
#include <hip/hip_bf16.h>

#define DEVFN static __device__ __forceinline__

constexpr int N_ = 128, S_ = 64, T_ = N_ * S_;
constexpr int E_ = 256, H_ = 512, NH_ = 8, DH_ = 32, L_ = 4;
constexpr int V_ = 33279, VPAD_ = 33280;

typedef __attribute__((ext_vector_type(8))) short bf16x8;
typedef __attribute__((ext_vector_type(4))) float f32x4;

DEVFN unsigned short f2bf(float f) {
  unsigned int u = __float_as_uint(f);
  unsigned int r = (u + 0x7fffu + ((u >> 16) & 1u)) >> 16;
  return (unsigned short)r;
}

DEVFN float geluf(float x) {
  return 0.5f * x * (1.f + erff(x * 0.70710678118654752440f));
}

DEVFN float block_sum(float v, float* sbuf) {
  #pragma unroll
  for (int off = 32; off >= 1; off >>= 1) v += __shfl_xor(v, off, 64);
  int lane = threadIdx.x & 63, wid = threadIdx.x >> 6;
  __syncthreads();
  if (lane == 0) sbuf[wid] = v;
  __syncthreads();
  return sbuf[0] + sbuf[1] + sbuf[2] + sbuf[3];
}

// ---------------- embedding + LN ----------------
__global__ __launch_bounds__(256) void k_embed_ln(
    const int* __restrict__ label, const int* __restrict__ mask,
    const float* __restrict__ emb, const float* __restrict__ pos,
    const float* __restrict__ g, const float* __restrict__ b,
    float* __restrict__ x) {
  __shared__ float sbuf[4];
  int t = blockIdx.x, tid = threadIdx.x;
  int s = t & (S_ - 1);
  int id = (mask[t] == 1) ? V_ : label[t];
  float v = emb[(size_t)id * E_ + tid] + pos[s * E_ + tid];
  float mean = block_sum(v, sbuf) * (1.f / E_);
  float d = v - mean;
  float var = block_sum(d * d, sbuf) * (1.f / E_);
  float rstd = 1.f / sqrtf(var + 1e-5f);
  x[(size_t)t * E_ + tid] = d * rstd * g[tid] + b[tid];
}

// ---------------- residual add + LN (b may be null) ----------------
__global__ __launch_bounds__(256) void k_add_ln(
    const float* __restrict__ a, const float* __restrict__ bsrc,
    const float* __restrict__ g, const float* __restrict__ bet,
    float* __restrict__ y) {
  __shared__ float sbuf[4];
  int t = blockIdx.x, tid = threadIdx.x;
  float v = a[(size_t)t * E_ + tid];
  if (bsrc) v += bsrc[(size_t)t * E_ + tid];
  float mean = block_sum(v, sbuf) * (1.f / E_);
  float d = v - mean;
  float var = block_sum(d * d, sbuf) * (1.f / E_);
  float rstd = 1.f / sqrtf(var + 1e-5f);
  y[(size_t)t * E_ + tid] = d * rstd * g[tid] + bet[tid];
}

// ---------------- fp32 GEMM: C[T][Eout] = X[T][EIN] @ W[EIN][Eout] + bias ----------------
template <int EIN, bool GELU>
__global__ __launch_bounds__(256) void k_gemm(
    const float* __restrict__ X, const float* __restrict__ W,
    const float* __restrict__ bias, float* __restrict__ C, int Eout) {
  constexpr int STR = EIN + 4;
  __shared__ float xs[16 * STR];
  int tid = threadIdx.x;
  int row0 = blockIdx.y * 16;
  int cq = tid & 15, r = tid >> 4;
  int c0 = blockIdx.x * 64 + cq * 4;
  for (int i = tid; i < 16 * EIN / 4; i += 256) {
    int rr = i / (EIN / 4), kk = (i % (EIN / 4)) * 4;
    *(float4*)&xs[rr * STR + kk] = *(const float4*)&X[(size_t)(row0 + rr) * EIN + kk];
  }
  __syncthreads();
  float ax = 0.f, ay = 0.f, az = 0.f, aw = 0.f;
  const float* xrow = &xs[r * STR];
  #pragma unroll 4
  for (int k = 0; k < EIN; k += 4) {
    float4 xv = *(const float4*)&xrow[k];
    const float* wr = &W[(size_t)k * Eout + c0];
    float4 w0 = *(const float4*)(wr);
    float4 w1 = *(const float4*)(wr + Eout);
    float4 w2 = *(const float4*)(wr + 2 * Eout);
    float4 w3 = *(const float4*)(wr + 3 * Eout);
    ax += xv.x * w0.x + xv.y * w1.x + xv.z * w2.x + xv.w * w3.x;
    ay += xv.x * w0.y + xv.y * w1.y + xv.z * w2.y + xv.w * w3.y;
    az += xv.x * w0.z + xv.y * w1.z + xv.z * w2.z + xv.w * w3.z;
    aw += xv.x * w0.w + xv.y * w1.w + xv.z * w2.w + xv.w * w3.w;
  }
  ax += bias[c0]; ay += bias[c0 + 1]; az += bias[c0 + 2]; aw += bias[c0 + 3];
  if (GELU) { ax = geluf(ax); ay = geluf(ay); az = geluf(az); aw = geluf(aw); }
  float4 res = {ax, ay, az, aw};
  *(float4*)&C[(size_t)(row0 + r) * Eout + c0] = res;
}

// ---------------- attention: one block per (n, h) ----------------
__global__ __launch_bounds__(256) void k_attn(
    const float* __restrict__ q, const float* __restrict__ k,
    const float* __restrict__ v, float* __restrict__ o) {
  __shared__ float qs[64 * 33], ks[64 * 33], vs[64 * 33], ps[64 * 68];
  int n = blockIdx.x >> 3, h = blockIdx.x & 7;
  int tid = threadIdx.x;
  const size_t base = (size_t)n * S_ * E_ + h * DH_;
  for (int i = tid; i < 64 * 32; i += 256) {
    int s = i >> 5, d = i & 31;
    size_t gidx = base + (size_t)s * E_ + d;
    qs[s * 33 + d] = q[gidx];
    ks[s * 33 + d] = k[gidx];
    vs[s * 33 + d] = v[gidx];
  }
  __syncthreads();
  int s = tid >> 2, part = tid & 3;
  float sc[16];
  #pragma unroll
  for (int tt = 0; tt < 16; tt++) sc[tt] = 0.f;
  const float* qrow = &qs[s * 33];
  #pragma unroll 8
  for (int d = 0; d < 32; d++) {
    float qv = qrow[d];
    #pragma unroll
    for (int tt = 0; tt < 16; tt++)
      sc[tt] += qv * ks[(part * 16 + tt) * 33 + d];
  }
  const float scale = 0.17677669529663687f;  // 1/sqrt(32)
  float m = -INFINITY;
  #pragma unroll
  for (int tt = 0; tt < 16; tt++) { sc[tt] *= scale; m = fmaxf(m, sc[tt]); }
  m = fmaxf(m, __shfl_xor(m, 1, 64));
  m = fmaxf(m, __shfl_xor(m, 2, 64));
  float sum = 0.f;
  #pragma unroll
  for (int tt = 0; tt < 16; tt++) { sc[tt] = __expf(sc[tt] - m); sum += sc[tt]; }
  sum += __shfl_xor(sum, 1, 64);
  sum += __shfl_xor(sum, 2, 64);
  float inv = 1.f / sum;
  #pragma unroll
  for (int tt = 0; tt < 16; tt++) ps[s * 68 + part * 16 + tt] = sc[tt] * inv;
  __syncthreads();
  float acc[8];
  #pragma unroll
  for (int dd = 0; dd < 8; dd++) acc[dd] = 0.f;
  int d0 = part * 8;
  for (int t2 = 0; t2 < 64; t2++) {
    float p = ps[s * 68 + t2];
    #pragma unroll
    for (int dd = 0; dd < 8; dd++) acc[dd] += p * vs[t2 * 33 + d0 + dd];
  }
  #pragma unroll
  for (int dd = 0; dd < 8; dd++)
    o[base + (size_t)s * E_ + d0 + dd] = acc[dd];
}

// ---------------- dW2 [E][V] f32 -> wt [VPAD][E] bf16 (transpose+convert) ----------------
__global__ __launch_bounds__(256) void k_w2t(const float* __restrict__ w,
                                             unsigned short* __restrict__ wt) {
  __shared__ float tile[32 * 33];
  int tx = threadIdx.x & 31, ty = threadIdx.x >> 5;
  int v0 = blockIdx.x * 32, k0 = blockIdx.y * 32;
  #pragma unroll
  for (int rr = 0; rr < 4; rr++) {
    int kk = ty * 4 + rr;
    int vv = v0 + tx;
    tile[kk * 33 + tx] = (vv < V_) ? w[(size_t)(k0 + kk) * V_ + vv] : 0.f;
  }
  __syncthreads();
  #pragma unroll
  for (int rr = 0; rr < 4; rr++) {
    int vv = ty * 4 + rr;
    wt[(size_t)(v0 + vv) * E_ + k0 + tx] = f2bf(tile[tx * 33 + vv]);
  }
}

// ---------------- f32 -> bf16 ----------------
__global__ __launch_bounds__(256) void k_to_bf16(const float* __restrict__ in,
                                                 unsigned short* __restrict__ o) {
  int i = blockIdx.x * 256 + threadIdx.x;
  o[i] = f2bf(in[i]);
}

// ---------------- vocab GEMM (MFMA bf16): out[n][v][s] = h[n][s][:]·dW2[:][v] + db2[v] ----------------
__global__ __launch_bounds__(256) void k_vocab(
    const unsigned short* __restrict__ hbf, const unsigned short* __restrict__ wt,
    const float* __restrict__ db2, float* __restrict__ out) {
  __shared__ unsigned short hs[64 * 264];  // [s][k], row stride 264 (bank-conflict pad)
  int n = blockIdx.x, vt = blockIdx.y;
  int tid = threadIdx.x, lane = tid & 63, wv = tid >> 6;
  const unsigned short* hsrc = hbf + (size_t)n * S_ * E_;
  for (int i = tid; i < (S_ * E_) / 8; i += 256) {
    int s = i >> 5, kc = (i & 31) * 8;
    *(uint4*)&hs[s * 264 + kc] = *(const uint4*)&hsrc[s * E_ + kc];
  }
  __syncthreads();
  int l15 = lane & 15, l4 = lane >> 4;
  // A = wt rows (m = v), 8 consecutive k per lane; B = hs rows (n = s)
  const unsigned short* Ap = wt + (size_t)(vt * 64 + wv * 16 + l15) * E_ + l4 * 8;
  f32x4 acc[4] = {};
  #pragma unroll
  for (int kb = 0; kb < 8; kb++) {
    bf16x8 a = *(const bf16x8*)(Ap + kb * 32);
    #pragma unroll
    for (int st = 0; st < 4; st++) {
      bf16x8 bfr = *(const bf16x8*)&hs[(st * 16 + l15) * 264 + kb * 32 + l4 * 8];
      acc[st] = __builtin_amdgcn_mfma_f32_16x16x32_bf16(a, bfr, acc[st], 0, 0, 0);
    }
  }
  #pragma unroll
  for (int j = 0; j < 4; j++) {
    int v = vt * 64 + wv * 16 + l4 * 4 + j;  // D row = (lane>>4)*4 + reg
    if (v < V_) {
      float bias = db2[v];
      size_t ob = ((size_t)n * V_ + v) * S_;
      #pragma unroll
      for (int st = 0; st < 4; st++)
        out[ob + st * 16 + l15] = acc[st][j] + bias;  // D col = lane&15
    }
  }
}

// ---------------- loss pass 1: per-token (logsumexp - logit[label]) ----------------
__global__ __launch_bounds__(256) void k_loss1(const float* __restrict__ out,
                                               const int* __restrict__ label,
                                               float* __restrict__ partial) {
  __shared__ float sm[256], ssum[256];
  int n = blockIdx.x, tid = threadIdx.x;
  int s = tid & 63, qq = tid >> 6;
  float m = -INFINITY, sum = 0.f;
  for (int v = qq; v < V_; v += 4) {
    float xv = out[((size_t)n * V_ + v) * S_ + s];
    float nm = fmaxf(m, xv);
    sum = sum * __expf(m - nm) + __expf(xv - nm);
    m = nm;
  }
  sm[tid] = m; ssum[tid] = sum;
  __syncthreads();
  if (qq == 0) {
    float M = sm[s], Sa = ssum[s];
    #pragma unroll
    for (int p = 1; p < 4; p++) {
      float m2 = sm[p * 64 + s], s2 = ssum[p * 64 + s];
      float nm = fmaxf(M, m2);
      Sa = Sa * __expf(M - nm) + s2 * __expf(m2 - nm);
      M = nm;
    }
    float lse = M + logf(Sa);
    int lab = label[n * S_ + s];
    float lx = out[((size_t)n * V_ + lab) * S_ + s];
    partial[n * S_ + s] = lse - lx;
  }
}

// ---------------- loss pass 2: deterministic mean ----------------
__global__ __launch_bounds__(256) void k_loss2(const float* __restrict__ partial,
                                               float* __restrict__ dst) {
  __shared__ float sbuf[4];
  int tid = threadIdx.x;
  float acc = 0.f;
  for (int i = tid; i < T_; i += 256) acc += partial[i];
  float tot = block_sum(acc, sbuf);
  if (tid == 0) dst[0] = tot / (float)T_;
}

extern "C" void kernel_launch(void* const* d_in, const int* in_sizes, int n_in,
                              void* d_out, int out_size, void* d_ws, size_t ws_size,
                              hipStream_t stream) {
  const int*   label = (const int*)d_in[0];
  const int*   mask  = (const int*)d_in[1];
  const float* emb   = (const float*)d_in[2];
  const float* pos   = (const float*)d_in[3];
  const float* emb_g = (const float*)d_in[4];
  const float* emb_b = (const float*)d_in[5];
  const float* Wq  = (const float*)d_in[6];
  const float* bq  = (const float*)d_in[7];
  const float* Wk  = (const float*)d_in[8];
  const float* bk  = (const float*)d_in[9];
  const float* Wv  = (const float*)d_in[10];
  const float* bv  = (const float*)d_in[11];
  const float* Wo  = (const float*)d_in[12];
  const float* bo  = (const float*)d_in[13];
  const float* n1g = (const float*)d_in[14];
  const float* n1b = (const float*)d_in[15];
  const float* W1  = (const float*)d_in[16];
  const float* b1  = (const float*)d_in[17];
  const float* W2  = (const float*)d_in[18];
  const float* b2  = (const float*)d_in[19];
  const float* n2g = (const float*)d_in[20];
  const float* n2b = (const float*)d_in[21];
  const float* dW1 = (const float*)d_in[22];
  const float* db1 = (const float*)d_in[23];
  const float* dng = (const float*)d_in[24];
  const float* dnb = (const float*)d_in[25];
  const float* dW2 = (const float*)d_in[26];
  const float* db2 = (const float*)d_in[27];
  float* out = (float*)d_out;
  (void)in_sizes; (void)n_in; (void)out_size; (void)ws_size;

  char* base = (char*)d_ws;
  size_t off = 0;
  auto alloc = [&](size_t bytes) {
    char* p = base + off;
    off += (bytes + 255) & ~(size_t)255;
    return p;
  };
  float* x   = (float*)alloc((size_t)T_ * E_ * 4);
  float* qb  = (float*)alloc((size_t)T_ * E_ * 4);
  float* kb  = (float*)alloc((size_t)T_ * E_ * 4);
  float* vb  = (float*)alloc((size_t)T_ * E_ * 4);
  float* ob  = (float*)alloc((size_t)T_ * E_ * 4);
  float* ffh = (float*)alloc((size_t)T_ * H_ * 4);
  unsigned short* hbf = (unsigned short*)alloc((size_t)T_ * E_ * 2);
  unsigned short* wt  = (unsigned short*)alloc((size_t)VPAD_ * E_ * 2);
  float* partial = (float*)alloc((size_t)T_ * 4);

  // independent: dW2 transpose/convert
  k_w2t<<<dim3(VPAD_ / 32, E_ / 32), 256, 0, stream>>>(dW2, wt);

  k_embed_ln<<<T_, 256, 0, stream>>>(label, mask, emb, pos, emb_g, emb_b, x);

  for (int l = 0; l < L_; l++) {
    const float* Wql = Wq + (size_t)l * E_ * E_;
    const float* Wkl = Wk + (size_t)l * E_ * E_;
    const float* Wvl = Wv + (size_t)l * E_ * E_;
    const float* Wol = Wo + (size_t)l * E_ * E_;
    k_gemm<E_, false><<<dim3(E_ / 64, T_ / 16), 256, 0, stream>>>(x, Wql, bq + l * E_, qb, E_);
    k_gemm<E_, false><<<dim3(E_ / 64, T_ / 16), 256, 0, stream>>>(x, Wkl, bk + l * E_, kb, E_);
    k_gemm<E_, false><<<dim3(E_ / 64, T_ / 16), 256, 0, stream>>>(x, Wvl, bv + l * E_, vb, E_);
    k_attn<<<N_ * NH_, 256, 0, stream>>>(qb, kb, vb, ob);
    k_gemm<E_, false><<<dim3(E_ / 64, T_ / 16), 256, 0, stream>>>(ob, Wol, bo + l * E_, qb, E_);
    k_add_ln<<<T_, 256, 0, stream>>>(x, qb, n1g + l * E_, n1b + l * E_, kb);          // x1 -> kb
    k_gemm<E_, true><<<dim3(H_ / 64, T_ / 16), 256, 0, stream>>>(kb, W1 + (size_t)l * E_ * H_, b1 + l * H_, ffh, H_);
    k_gemm<H_, false><<<dim3(E_ / 64, T_ / 16), 256, 0, stream>>>(ffh, W2 + (size_t)l * H_ * E_, b2 + l * E_, vb, E_);
    k_add_ln<<<T_, 256, 0, stream>>>(kb, vb, n2g + l * E_, n2b + l * E_, x);          // x2 -> x
  }

  // decoder head
  k_gemm<E_, true><<<dim3(E_ / 64, T_ / 16), 256, 0, stream>>>(x, dW1, db1, qb, E_);  // gelu(x@dW1+db1)
  k_add_ln<<<T_, 256, 0, stream>>>(qb, nullptr, dng, dnb, kb);                        // LN -> kb
  k_to_bf16<<<T_, 256, 0, stream>>>(kb, hbf);

  // vocab projection + transposed store
  k_vocab<<<dim3(N_, VPAD_ / 64), 256, 0, stream>>>(hbf, wt, db2, out);

  // loss
  k_loss1<<<N_, 256, 0, stream>>>(out, label, partial);
  k_loss2<<<1, 256, 0, stream>>>(partial, out + (size_t)N_ * V_ * S_);
}

// Round 2
// 3073.696 us; speedup vs baseline: 2.1608x; 2.1608x over previous
//
#include <hip/hip_runtime.h>
#include <hip/hip_bf16.h>

#define DEVFN static __device__ __forceinline__

constexpr int N_ = 128, S_ = 64, T_ = N_ * S_;
constexpr int E_ = 256, H_ = 512, NH_ = 8, DH_ = 32, L_ = 4;
constexpr int V_ = 33279, VPAD_ = 33280, VT_ = VPAD_ / 64;  // 520 v-tiles

typedef __attribute__((ext_vector_type(8))) short bf16x8;
typedef __attribute__((ext_vector_type(4))) float f32x4;

DEVFN unsigned short f2bf(float f) {
  unsigned int u = __float_as_uint(f);
  unsigned int r = (u + 0x7fffu + ((u >> 16) & 1u)) >> 16;
  return (unsigned short)r;
}

DEVFN float geluf(float x) {
  return 0.5f * x * (1.f + erff(x * 0.70710678118654752440f));
}

DEVFN float block_sum(float v, float* sbuf) {
  #pragma unroll
  for (int off = 32; off >= 1; off >>= 1) v += __shfl_xor(v, off, 64);
  int lane = threadIdx.x & 63, wid = threadIdx.x >> 6;
  __syncthreads();
  if (lane == 0) sbuf[wid] = v;
  __syncthreads();
  return sbuf[0] + sbuf[1] + sbuf[2] + sbuf[3];
}

// ---------------- embedding + LN ----------------
__global__ __launch_bounds__(256) void k_embed_ln(
    const int* __restrict__ label, const int* __restrict__ mask,
    const float* __restrict__ emb, const float* __restrict__ pos,
    const float* __restrict__ g, const float* __restrict__ b,
    float* __restrict__ x) {
  __shared__ float sbuf[4];
  int t = blockIdx.x, tid = threadIdx.x;
  int s = t & (S_ - 1);
  int id = (mask[t] == 1) ? V_ : label[t];
  float v = emb[(size_t)id * E_ + tid] + pos[s * E_ + tid];
  float mean = block_sum(v, sbuf) * (1.f / E_);
  float d = v - mean;
  float var = block_sum(d * d, sbuf) * (1.f / E_);
  float rstd = 1.f / sqrtf(var + 1e-5f);
  x[(size_t)t * E_ + tid] = d * rstd * g[tid] + b[tid];
}

// ---------------- residual add + LN (b may be null) ----------------
__global__ __launch_bounds__(256) void k_add_ln(
    const float* __restrict__ a, const float* __restrict__ bsrc,
    const float* __restrict__ g, const float* __restrict__ bet,
    float* __restrict__ y) {
  __shared__ float sbuf[4];
  int t = blockIdx.x, tid = threadIdx.x;
  float v = a[(size_t)t * E_ + tid];
  if (bsrc) v += bsrc[(size_t)t * E_ + tid];
  float mean = block_sum(v, sbuf) * (1.f / E_);
  float d = v - mean;
  float var = block_sum(d * d, sbuf) * (1.f / E_);
  float rstd = 1.f / sqrtf(var + 1e-5f);
  y[(size_t)t * E_ + tid] = d * rstd * g[tid] + bet[tid];
}

// ---------------- fp32 GEMM: C[T][Eout] = X[T][EIN] @ W[EIN][Eout] + bias ----------------
template <int EIN, bool GELU>
__global__ __launch_bounds__(256) void k_gemm(
    const float* __restrict__ X, const float* __restrict__ W,
    const float* __restrict__ bias, float* __restrict__ C, int Eout) {
  constexpr int STR = EIN + 4;
  __shared__ float xs[16 * STR];
  int tid = threadIdx.x;
  int row0 = blockIdx.y * 16;
  int cq = tid & 15, r = tid >> 4;
  int c0 = blockIdx.x * 64 + cq * 4;
  for (int i = tid; i < 16 * EIN / 4; i += 256) {
    int rr = i / (EIN / 4), kk = (i % (EIN / 4)) * 4;
    *(float4*)&xs[rr * STR + kk] = *(const float4*)&X[(size_t)(row0 + rr) * EIN + kk];
  }
  __syncthreads();
  float ax = 0.f, ay = 0.f, az = 0.f, aw = 0.f;
  const float* xrow = &xs[r * STR];
  #pragma unroll 4
  for (int k = 0; k < EIN; k += 4) {
    float4 xv = *(const float4*)&xrow[k];
    const float* wr = &W[(size_t)k * Eout + c0];
    float4 w0 = *(const float4*)(wr);
    float4 w1 = *(const float4*)(wr + Eout);
    float4 w2 = *(const float4*)(wr + 2 * Eout);
    float4 w3 = *(const float4*)(wr + 3 * Eout);
    ax += xv.x * w0.x + xv.y * w1.x + xv.z * w2.x + xv.w * w3.x;
    ay += xv.x * w0.y + xv.y * w1.y + xv.z * w2.y + xv.w * w3.y;
    az += xv.x * w0.z + xv.y * w1.z + xv.z * w2.z + xv.w * w3.z;
    aw += xv.x * w0.w + xv.y * w1.w + xv.z * w2.w + xv.w * w3.w;
  }
  ax += bias[c0]; ay += bias[c0 + 1]; az += bias[c0 + 2]; aw += bias[c0 + 3];
  if (GELU) { ax = geluf(ax); ay = geluf(ay); az = geluf(az); aw = geluf(aw); }
  float4 res = {ax, ay, az, aw};
  *(float4*)&C[(size_t)(row0 + r) * Eout + c0] = res;
}

// ---------------- attention: one block per (n, h) ----------------
__global__ __launch_bounds__(256) void k_attn(
    const float* __restrict__ q, const float* __restrict__ k,
    const float* __restrict__ v, float* __restrict__ o) {
  __shared__ float qs[64 * 33], ks[64 * 33], vs[64 * 33], ps[64 * 68];
  int n = blockIdx.x >> 3, h = blockIdx.x & 7;
  int tid = threadIdx.x;
  const size_t base = (size_t)n * S_ * E_ + h * DH_;
  for (int i = tid; i < 64 * 32; i += 256) {
    int s = i >> 5, d = i & 31;
    size_t gidx = base + (size_t)s * E_ + d;
    qs[s * 33 + d] = q[gidx];
    ks[s * 33 + d] = k[gidx];
    vs[s * 33 + d] = v[gidx];
  }
  __syncthreads();
  int s = tid >> 2, part = tid & 3;
  float sc[16];
  #pragma unroll
  for (int tt = 0; tt < 16; tt++) sc[tt] = 0.f;
  const float* qrow = &qs[s * 33];
  #pragma unroll 8
  for (int d = 0; d < 32; d++) {
    float qv = qrow[d];
    #pragma unroll
    for (int tt = 0; tt < 16; tt++)
      sc[tt] += qv * ks[(part * 16 + tt) * 33 + d];
  }
  const float scale = 0.17677669529663687f;  // 1/sqrt(32)
  float m = -INFINITY;
  #pragma unroll
  for (int tt = 0; tt < 16; tt++) { sc[tt] *= scale; m = fmaxf(m, sc[tt]); }
  m = fmaxf(m, __shfl_xor(m, 1, 64));
  m = fmaxf(m, __shfl_xor(m, 2, 64));
  float sum = 0.f;
  #pragma unroll
  for (int tt = 0; tt < 16; tt++) { sc[tt] = __expf(sc[tt] - m); sum += sc[tt]; }
  sum += __shfl_xor(sum, 1, 64);
  sum += __shfl_xor(sum, 2, 64);
  float inv = 1.f / sum;
  #pragma unroll
  for (int tt = 0; tt < 16; tt++) ps[s * 68 + part * 16 + tt] = sc[tt] * inv;
  __syncthreads();
  float acc[8];
  #pragma unroll
  for (int dd = 0; dd < 8; dd++) acc[dd] = 0.f;
  int d0 = part * 8;
  for (int t2 = 0; t2 < 64; t2++) {
    float p = ps[s * 68 + t2];
    #pragma unroll
    for (int dd = 0; dd < 8; dd++) acc[dd] += p * vs[t2 * 33 + d0 + dd];
  }
  #pragma unroll
  for (int dd = 0; dd < 8; dd++)
    o[base + (size_t)s * E_ + d0 + dd] = acc[dd];
}

// ---------------- dW2 [E][V] f32 -> wt [VPAD][E] bf16 (transpose+convert) ----------------
__global__ __launch_bounds__(256) void k_w2t(const float* __restrict__ w,
                                             unsigned short* __restrict__ wt) {
  __shared__ float tile[32 * 33];
  int tx = threadIdx.x & 31, ty = threadIdx.x >> 5;
  int v0 = blockIdx.x * 32, k0 = blockIdx.y * 32;
  #pragma unroll
  for (int rr = 0; rr < 4; rr++) {
    int kk = ty * 4 + rr;
    int vv = v0 + tx;
    tile[kk * 33 + tx] = (vv < V_) ? w[(size_t)(k0 + kk) * V_ + vv] : 0.f;
  }
  __syncthreads();
  #pragma unroll
  for (int rr = 0; rr < 4; rr++) {
    int vv = ty * 4 + rr;
    wt[(size_t)(v0 + vv) * E_ + k0 + tx] = f2bf(tile[tx * 33 + vv]);
  }
}

// ---------------- f32 -> bf16 ----------------
__global__ __launch_bounds__(256) void k_to_bf16(const float* __restrict__ in,
                                                 unsigned short* __restrict__ o) {
  int i = blockIdx.x * 256 + threadIdx.x;
  o[i] = f2bf(in[i]);
}

// ---------------- vocab GEMM (MFMA bf16) + fused softmax partials ----------------
// out[n][v][s] = h[n][s][:]·dW2[:][v] + db2[v]; also per-(n,s,vtile) (max, sumexp)
__global__ __launch_bounds__(256) void k_vocab(
    const unsigned short* __restrict__ hbf, const unsigned short* __restrict__ wt,
    const float* __restrict__ db2, float* __restrict__ out,
    float* __restrict__ pmax, float* __restrict__ psum) {
  __shared__ unsigned short hs[64 * 264];  // [s][k], row stride 264 (bank-conflict pad)
  __shared__ float redm[4][64];            // [wave][s]
  __shared__ float reds[4][64];
  int n = blockIdx.x, vt = blockIdx.y;
  int tid = threadIdx.x, lane = tid & 63, wv = tid >> 6;
  const unsigned short* hsrc = hbf + (size_t)n * S_ * E_;
  for (int i = tid; i < (S_ * E_) / 8; i += 256) {
    int s = i >> 5, kc = (i & 31) * 8;
    *(uint4*)&hs[s * 264 + kc] = *(const uint4*)&hsrc[s * E_ + kc];
  }
  __syncthreads();
  int l15 = lane & 15, l4 = lane >> 4;
  // A = wt rows (m = v), 8 consecutive k per lane; B = hs rows (n = s)
  const unsigned short* Ap = wt + (size_t)(vt * 64 + wv * 16 + l15) * E_ + l4 * 8;
  f32x4 acc[4] = {};
  #pragma unroll
  for (int kb = 0; kb < 8; kb++) {
    bf16x8 a = *(const bf16x8*)(Ap + kb * 32);
    #pragma unroll
    for (int st = 0; st < 4; st++) {
      bf16x8 bfr = *(const bf16x8*)&hs[(st * 16 + l15) * 264 + kb * 32 + l4 * 8];
      acc[st] = __builtin_amdgcn_mfma_f32_16x16x32_bf16(a, bfr, acc[st], 0, 0, 0);
    }
  }
  // vals[st][j]: logit for v = vt*64 + wv*16 + l4*4 + j, s = st*16 + l15
  float vals[4][4];
  #pragma unroll
  for (int j = 0; j < 4; j++) {
    int v = vt * 64 + wv * 16 + l4 * 4 + j;
    bool valid = v < V_;
    float bias = valid ? db2[v] : 0.f;
    size_t ob = ((size_t)n * V_ + v) * S_;
    #pragma unroll
    for (int st = 0; st < 4; st++) {
      float val = valid ? (acc[st][j] + bias) : -INFINITY;
      vals[st][j] = val;
      if (valid) out[ob + st * 16 + l15] = val;
    }
  }
  // per-s max over this block's 64 v's
  float lm[4];
  #pragma unroll
  for (int st = 0; st < 4; st++) {
    float m = fmaxf(fmaxf(vals[st][0], vals[st][1]), fmaxf(vals[st][2], vals[st][3]));
    m = fmaxf(m, __shfl_xor(m, 16, 64));
    m = fmaxf(m, __shfl_xor(m, 32, 64));
    lm[st] = m;  // max over this wave's 16 v, for s = st*16+l15
  }
  if (l4 == 0) {
    #pragma unroll
    for (int st = 0; st < 4; st++) redm[wv][st * 16 + l15] = lm[st];
  }
  __syncthreads();
  float bm[4], ls[4];
  #pragma unroll
  for (int st = 0; st < 4; st++) {
    int s = st * 16 + l15;
    bm[st] = fmaxf(fmaxf(redm[0][s], redm[1][s]), fmaxf(redm[2][s], redm[3][s]));
    float sum = 0.f;
    #pragma unroll
    for (int j = 0; j < 4; j++) sum += __expf(vals[st][j] - bm[st]);  // exp(-inf)=0
    sum += __shfl_xor(sum, 16, 64);
    sum += __shfl_xor(sum, 32, 64);
    ls[st] = sum;
  }
  if (l4 == 0) {
    #pragma unroll
    for (int st = 0; st < 4; st++) reds[wv][st * 16 + l15] = ls[st];
  }
  __syncthreads();
  if (wv == 0 && l4 == 0) {
    #pragma unroll
    for (int st = 0; st < 4; st++) {
      int s = st * 16 + l15;
      float bs = reds[0][s] + reds[1][s] + reds[2][s] + reds[3][s];
      size_t pi = ((size_t)n * VT_ + vt) * S_ + s;
      pmax[pi] = bm[st];
      psum[pi] = bs;
    }
  }
}

// ---------------- loss finalize: merge per-vtile partials -> per-token loss ----------------
__global__ __launch_bounds__(256) void k_lossf(
    const float* __restrict__ pmax, const float* __restrict__ psum,
    const float* __restrict__ out, const int* __restrict__ label,
    float* __restrict__ partial) {
  __shared__ float sm[256], ssum[256];
  int n = blockIdx.x, tid = threadIdx.x;
  int s = tid & 63, qq = tid >> 6;
  float m = -INFINITY, sum = 0.f;
  for (int vt = qq; vt < VT_; vt += 4) {
    size_t pi = ((size_t)n * VT_ + vt) * S_ + s;
    float m2 = pmax[pi], s2 = psum[pi];
    float nm = fmaxf(m, m2);
    sum = sum * __expf(m - nm) + s2 * __expf(m2 - nm);
    m = nm;
  }
  sm[tid] = m; ssum[tid] = sum;
  __syncthreads();
  if (qq == 0) {
    float M = sm[s], Sa = ssum[s];
    #pragma unroll
    for (int p = 1; p < 4; p++) {
      float m2 = sm[p * 64 + s], s2 = ssum[p * 64 + s];
      float nm = fmaxf(M, m2);
      Sa = Sa * __expf(M - nm) + s2 * __expf(m2 - nm);
      M = nm;
    }
    float lse = M + logf(Sa);
    int lab = label[n * S_ + s];
    float lx = out[((size_t)n * V_ + lab) * S_ + s];
    partial[n * S_ + s] = lse - lx;
  }
}

// ---------------- loss pass 2: deterministic mean ----------------
__global__ __launch_bounds__(256) void k_loss2(const float* __restrict__ partial,
                                               float* __restrict__ dst) {
  __shared__ float sbuf[4];
  int tid = threadIdx.x;
  float acc = 0.f;
  for (int i = tid; i < T_; i += 256) acc += partial[i];
  float tot = block_sum(acc, sbuf);
  if (tid == 0) dst[0] = tot / (float)T_;
}

extern "C" void kernel_launch(void* const* d_in, const int* in_sizes, int n_in,
                              void* d_out, int out_size, void* d_ws, size_t ws_size,
                              hipStream_t stream) {
  const int*   label = (const int*)d_in[0];
  const int*   mask  = (const int*)d_in[1];
  const float* emb   = (const float*)d_in[2];
  const float* pos   = (const float*)d_in[3];
  const float* emb_g = (const float*)d_in[4];
  const float* emb_b = (const float*)d_in[5];
  const float* Wq  = (const float*)d_in[6];
  const float* bq  = (const float*)d_in[7];
  const float* Wk  = (const float*)d_in[8];
  const float* bk  = (const float*)d_in[9];
  const float* Wv  = (const float*)d_in[10];
  const float* bv  = (const float*)d_in[11];
  const float* Wo  = (const float*)d_in[12];
  const float* bo  = (const float*)d_in[13];
  const float* n1g = (const float*)d_in[14];
  const float* n1b = (const float*)d_in[15];
  const float* W1  = (const float*)d_in[16];
  const float* b1  = (const float*)d_in[17];
  const float* W2  = (const float*)d_in[18];
  const float* b2  = (const float*)d_in[19];
  const float* n2g = (const float*)d_in[20];
  const float* n2b = (const float*)d_in[21];
  const float* dW1 = (const float*)d_in[22];
  const float* db1 = (const float*)d_in[23];
  const float* dng = (const float*)d_in[24];
  const float* dnb = (const float*)d_in[25];
  const float* dW2 = (const float*)d_in[26];
  const float* db2 = (const float*)d_in[27];
  float* out = (float*)d_out;
  (void)in_sizes; (void)n_in; (void)out_size; (void)ws_size;

  char* base = (char*)d_ws;
  size_t off = 0;
  auto alloc = [&](size_t bytes) {
    char* p = base + off;
    off += (bytes + 255) & ~(size_t)255;
    return p;
  };
  float* x   = (float*)alloc((size_t)T_ * E_ * 4);
  float* qb  = (float*)alloc((size_t)T_ * E_ * 4);
  float* kb  = (float*)alloc((size_t)T_ * E_ * 4);
  float* vb  = (float*)alloc((size_t)T_ * E_ * 4);
  float* ob  = (float*)alloc((size_t)T_ * E_ * 4);
  float* ffh = (float*)alloc((size_t)T_ * H_ * 4);
  unsigned short* hbf = (unsigned short*)alloc((size_t)T_ * E_ * 2);
  unsigned short* wt  = (unsigned short*)alloc((size_t)VPAD_ * E_ * 2);
  float* partial = (float*)alloc((size_t)T_ * 4);
  // softmax partials alias the x..ffh region (dead by k_vocab time):
  // need 2 * N*VT*S floats = 2*17.04 MB < 58.7 MB region size.
  float* pmax = x;
  float* psum = x + (size_t)N_ * VT_ * S_;

  // independent: dW2 transpose/convert
  k_w2t<<<dim3(VPAD_ / 32, E_ / 32), 256, 0, stream>>>(dW2, wt);

  k_embed_ln<<<T_, 256, 0, stream>>>(label, mask, emb, pos, emb_g, emb_b, x);

  for (int l = 0; l < L_; l++) {
    const float* Wql = Wq + (size_t)l * E_ * E_;
    const float* Wkl = Wk + (size_t)l * E_ * E_;
    const float* Wvl = Wv + (size_t)l * E_ * E_;
    const float* Wol = Wo + (size_t)l * E_ * E_;
    k_gemm<E_, false><<<dim3(E_ / 64, T_ / 16), 256, 0, stream>>>(x, Wql, bq + l * E_, qb, E_);
    k_gemm<E_, false><<<dim3(E_ / 64, T_ / 16), 256, 0, stream>>>(x, Wkl, bk + l * E_, kb, E_);
    k_gemm<E_, false><<<dim3(E_ / 64, T_ / 16), 256, 0, stream>>>(x, Wvl, bv + l * E_, vb, E_);
    k_attn<<<N_ * NH_, 256, 0, stream>>>(qb, kb, vb, ob);
    k_gemm<E_, false><<<dim3(E_ / 64, T_ / 16), 256, 0, stream>>>(ob, Wol, bo + l * E_, qb, E_);
    k_add_ln<<<T_, 256, 0, stream>>>(x, qb, n1g + l * E_, n1b + l * E_, kb);          // x1 -> kb
    k_gemm<E_, true><<<dim3(H_ / 64, T_ / 16), 256, 0, stream>>>(kb, W1 + (size_t)l * E_ * H_, b1 + l * H_, ffh, H_);
    k_gemm<H_, false><<<dim3(E_ / 64, T_ / 16), 256, 0, stream>>>(ffh, W2 + (size_t)l * H_ * E_, b2 + l * E_, vb, E_);
    k_add_ln<<<T_, 256, 0, stream>>>(kb, vb, n2g + l * E_, n2b + l * E_, x);          // x2 -> x
  }

  // decoder head
  k_gemm<E_, true><<<dim3(E_ / 64, T_ / 16), 256, 0, stream>>>(x, dW1, db1, qb, E_);  // gelu(x@dW1+db1)
  k_add_ln<<<T_, 256, 0, stream>>>(qb, nullptr, dng, dnb, kb);                        // LN -> kb
  k_to_bf16<<<T_, 256, 0, stream>>>(kb, hbf);

  // vocab projection + transposed store + fused softmax partials
  // (pmax/psum alias x.. region: x is dead from here on)
  k_vocab<<<dim3(N_, VT_), 256, 0, stream>>>(hbf, wt, db2, out, pmax, psum);

  // loss
  k_lossf<<<N_, 256, 0, stream>>>(pmax, psum, out, label, partial);
  k_loss2<<<1, 256, 0, stream>>>(partial, out + (size_t)N_ * V_ * S_);
}

// Round 3
// 1239.180 us; speedup vs baseline: 5.3598x; 2.4804x over previous
//
#include <hip/hip_runtime.h>
#include <hip/hip_bf16.h>

#define DEVFN static __device__ __forceinline__

constexpr int N_ = 128, S_ = 64, T_ = N_ * S_;
constexpr int E_ = 256, H_ = 512, NH_ = 8, DH_ = 32, L_ = 4;
constexpr int V_ = 33279, VPAD_ = 33280, VT_ = VPAD_ / 64;  // 520 v-tiles

typedef __attribute__((ext_vector_type(8))) short bf16x8;
typedef __attribute__((ext_vector_type(4))) float f32x4;
typedef unsigned short ushort_t;

DEVFN ushort_t f2bf(float f) {
  unsigned int u = __float_as_uint(f);
  unsigned int r = (u + 0x7fffu + ((u >> 16) & 1u)) >> 16;
  return (ushort_t)r;
}
DEVFN float bf2f(ushort_t u) { return __uint_as_float(((unsigned)u) << 16); }

DEVFN float geluf(float x) {
  return 0.5f * x * (1.f + erff(x * 0.70710678118654752440f));
}

DEVFN float block_sum(float v, float* sbuf) {
  #pragma unroll
  for (int off = 32; off >= 1; off >>= 1) v += __shfl_xor(v, off, 64);
  int lane = threadIdx.x & 63, wid = threadIdx.x >> 6;
  __syncthreads();
  if (lane == 0) sbuf[wid] = v;
  __syncthreads();
  return sbuf[0] + sbuf[1] + sbuf[2] + sbuf[3];
}

// ---------------- embedding + LN (f32 + bf16 out) ----------------
__global__ __launch_bounds__(256) void k_embed_ln(
    const int* __restrict__ label, const int* __restrict__ mask,
    const float* __restrict__ emb, const float* __restrict__ pos,
    const float* __restrict__ g, const float* __restrict__ b,
    float* __restrict__ x, ushort_t* __restrict__ xb) {
  __shared__ float sbuf[4];
  int t = blockIdx.x, tid = threadIdx.x;
  int s = t & (S_ - 1);
  int id = (mask[t] == 1) ? V_ : label[t];
  float v = emb[(size_t)id * E_ + tid] + pos[s * E_ + tid];
  float mean = block_sum(v, sbuf) * (1.f / E_);
  float d = v - mean;
  float var = block_sum(d * d, sbuf) * (1.f / E_);
  float rstd = 1.f / sqrtf(var + 1e-5f);
  float y = d * rstd * g[tid] + b[tid];
  x[(size_t)t * E_ + tid] = y;
  xb[(size_t)t * E_ + tid] = f2bf(y);
}

// ---------------- residual add + LN (optional f32 / bf16 outputs) ----------------
__global__ __launch_bounds__(256) void k_add_ln(
    const float* __restrict__ a, const float* __restrict__ bsrc,
    const float* __restrict__ g, const float* __restrict__ bet,
    float* __restrict__ y, ushort_t* __restrict__ yb) {
  __shared__ float sbuf[4];
  int t = blockIdx.x, tid = threadIdx.x;
  float v = a[(size_t)t * E_ + tid];
  if (bsrc) v += bsrc[(size_t)t * E_ + tid];
  float mean = block_sum(v, sbuf) * (1.f / E_);
  float d = v - mean;
  float var = block_sum(d * d, sbuf) * (1.f / E_);
  float rstd = 1.f / sqrtf(var + 1e-5f);
  float o = d * rstd * g[tid] + bet[tid];
  if (y)  y[(size_t)t * E_ + tid] = o;
  if (yb) yb[(size_t)t * E_ + tid] = f2bf(o);
}

// ---------------- bias concat: bqkv[l][0:256)=bq, [256:512)=bk, [512:768)=bv ----
__global__ __launch_bounds__(256) void k_bcat(
    const float* __restrict__ bq, const float* __restrict__ bk,
    const float* __restrict__ bv, float* __restrict__ bqkv) {
  int l = blockIdx.x, i = threadIdx.x;
  bqkv[l * 768 + i]       = bq[l * 256 + i];
  bqkv[l * 768 + 256 + i] = bk[l * 256 + i];
  bqkv[l * 768 + 512 + i] = bv[l * 256 + i];
}

// ---------------- generic transpose+convert: src[L][K][J] f32 -> dst[L][J][K] bf16
__global__ __launch_bounds__(256) void k_wt(const float* __restrict__ src,
                                            ushort_t* __restrict__ dst,
                                            int K, int J, int dstLayerStride) {
  __shared__ float tile[32][33];
  int j0 = blockIdx.x * 32, k0 = blockIdx.y * 32, l = blockIdx.z;
  src += (size_t)l * K * J;
  dst += (size_t)l * dstLayerStride;
  int tx = threadIdx.x & 31, ty = threadIdx.x >> 5;
  #pragma unroll
  for (int rr = 0; rr < 4; rr++) {
    int kk = ty * 4 + rr;
    tile[kk][tx] = src[(size_t)(k0 + kk) * J + j0 + tx];
  }
  __syncthreads();
  #pragma unroll
  for (int rr = 0; rr < 4; rr++) {
    int jj = ty * 4 + rr;
    dst[(size_t)(j0 + jj) * K + k0 + tx] = f2bf(tile[tx][jj]);
  }
}

// ---------------- MFMA GEMM: C[T][Nout] = Xb[T][K] @ WT[Nout][K]^T + bias ----------
// 64x64 tile per block; 4 waves, wave wv owns t-rows [wv*16, wv*16+16).
template <int K, int OUT_BF16, int GELU_>
__global__ __launch_bounds__(256) void k_mm(
    const ushort_t* __restrict__ Xb, const ushort_t* __restrict__ WT,
    const float* __restrict__ bias, void* __restrict__ C, int Nout) {
  constexpr int STR = K + 8;  // shorts; stride = (K+8)*2 B = 4 mod 32 words -> free 2-way
  __shared__ ushort_t xs[64 * STR];
  int tid = threadIdx.x, lane = tid & 63, wv = tid >> 6;
  int t0 = blockIdx.x * 64, j0 = blockIdx.y * 64;
  const ushort_t* xsrc = Xb + (size_t)t0 * K;
  for (int i = tid; i < 64 * (K / 8); i += 256) {
    int r = i / (K / 8), c = (i % (K / 8)) * 8;
    *(uint4*)&xs[r * STR + c] = *(const uint4*)&xsrc[(size_t)r * K + c];
  }
  __syncthreads();
  int l15 = lane & 15, l4 = lane >> 4;
  f32x4 acc[4] = {};
  const ushort_t* xrow = &xs[(wv * 16 + l15) * STR + l4 * 8];
  const ushort_t* wrow = WT + (size_t)j0 * K + l4 * 8;
  #pragma unroll
  for (int kb = 0; kb < K / 32; kb++) {
    bf16x8 a = *(const bf16x8*)(xrow + kb * 32);
    #pragma unroll
    for (int st = 0; st < 4; st++) {
      bf16x8 bfr = *(const bf16x8*)(wrow + (size_t)(st * 16 + l15) * K + kb * 32);
      acc[st] = __builtin_amdgcn_mfma_f32_16x16x32_bf16(a, bfr, acc[st], 0, 0, 0);
    }
  }
  #pragma unroll
  for (int st = 0; st < 4; st++) {
    int j = j0 + st * 16 + l15;
    float bv_ = bias[j];
    #pragma unroll
    for (int r = 0; r < 4; r++) {
      float val = acc[st][r] + bv_;
      if (GELU_) val = geluf(val);
      int t = t0 + wv * 16 + l4 * 4 + r;
      if (OUT_BF16)
        ((ushort_t*)C)[(size_t)t * Nout + j] = f2bf(val);
      else
        ((float*)C)[(size_t)t * Nout + j] = val;
    }
  }
}

// ---------------- attention: one block per (n, h); qkv packed [T][768] bf16 ------
__global__ __launch_bounds__(256) void k_attn(
    const ushort_t* __restrict__ qkv, ushort_t* __restrict__ o) {
  __shared__ float qs[64 * 33], ks[64 * 33], vs[64 * 33], ps[64 * 68];
  int n = blockIdx.x >> 3, h = blockIdx.x & 7;
  int tid = threadIdx.x;
  for (int i = tid; i < S_ * DH_; i += 256) {
    int s = i >> 5, d = i & 31;
    size_t g = (size_t)(n * S_ + s) * 768 + h * DH_ + d;
    qs[s * 33 + d] = bf2f(qkv[g]);
    ks[s * 33 + d] = bf2f(qkv[g + 256]);
    vs[s * 33 + d] = bf2f(qkv[g + 512]);
  }
  __syncthreads();
  int s = tid >> 2, part = tid & 3;
  float sc[16];
  #pragma unroll
  for (int tt = 0; tt < 16; tt++) sc[tt] = 0.f;
  const float* qrow = &qs[s * 33];
  #pragma unroll 8
  for (int d = 0; d < 32; d++) {
    float qv = qrow[d];
    #pragma unroll
    for (int tt = 0; tt < 16; tt++)
      sc[tt] += qv * ks[(part * 16 + tt) * 33 + d];
  }
  const float scale = 0.17677669529663687f;  // 1/sqrt(32)
  float m = -INFINITY;
  #pragma unroll
  for (int tt = 0; tt < 16; tt++) { sc[tt] *= scale; m = fmaxf(m, sc[tt]); }
  m = fmaxf(m, __shfl_xor(m, 1, 64));
  m = fmaxf(m, __shfl_xor(m, 2, 64));
  float sum = 0.f;
  #pragma unroll
  for (int tt = 0; tt < 16; tt++) { sc[tt] = __expf(sc[tt] - m); sum += sc[tt]; }
  sum += __shfl_xor(sum, 1, 64);
  sum += __shfl_xor(sum, 2, 64);
  float inv = 1.f / sum;
  #pragma unroll
  for (int tt = 0; tt < 16; tt++) ps[s * 68 + part * 16 + tt] = sc[tt] * inv;
  __syncthreads();
  float acc[8];
  #pragma unroll
  for (int dd = 0; dd < 8; dd++) acc[dd] = 0.f;
  int d0 = part * 8;
  for (int t2 = 0; t2 < 64; t2++) {
    float p = ps[s * 68 + t2];
    #pragma unroll
    for (int dd = 0; dd < 8; dd++) acc[dd] += p * vs[t2 * 33 + d0 + dd];
  }
  #pragma unroll
  for (int dd = 0; dd < 8; dd++)
    o[(size_t)(n * S_ + s) * E_ + h * DH_ + d0 + dd] = f2bf(acc[dd]);
}

// ---------------- dW2 [E][V] f32 -> wt [VPAD][E] bf16 (transpose+convert) --------
__global__ __launch_bounds__(256) void k_w2t(const float* __restrict__ w,
                                             ushort_t* __restrict__ wt) {
  __shared__ float tile[32 * 33];
  int tx = threadIdx.x & 31, ty = threadIdx.x >> 5;
  int v0 = blockIdx.x * 32, k0 = blockIdx.y * 32;
  #pragma unroll
  for (int rr = 0; rr < 4; rr++) {
    int kk = ty * 4 + rr;
    int vv = v0 + tx;
    tile[kk * 33 + tx] = (vv < V_) ? w[(size_t)(k0 + kk) * V_ + vv] : 0.f;
  }
  __syncthreads();
  #pragma unroll
  for (int rr = 0; rr < 4; rr++) {
    int vv = ty * 4 + rr;
    wt[(size_t)(v0 + vv) * E_ + k0 + tx] = f2bf(tile[tx * 33 + vv]);
  }
}

// ---------------- vocab GEMM (MFMA bf16) + fused softmax partials ----------------
__global__ __launch_bounds__(256) void k_vocab(
    const ushort_t* __restrict__ hbf, const ushort_t* __restrict__ wt,
    const float* __restrict__ db2, float* __restrict__ out,
    float* __restrict__ pmax, float* __restrict__ psum) {
  __shared__ ushort_t hs[64 * 264];
  __shared__ float redm[4][64];
  __shared__ float reds[4][64];
  int n = blockIdx.x, vt = blockIdx.y;
  int tid = threadIdx.x, lane = tid & 63, wv = tid >> 6;
  const ushort_t* hsrc = hbf + (size_t)n * S_ * E_;
  for (int i = tid; i < (S_ * E_) / 8; i += 256) {
    int s = i >> 5, kc = (i & 31) * 8;
    *(uint4*)&hs[s * 264 + kc] = *(const uint4*)&hsrc[s * E_ + kc];
  }
  __syncthreads();
  int l15 = lane & 15, l4 = lane >> 4;
  const ushort_t* Ap = wt + (size_t)(vt * 64 + wv * 16 + l15) * E_ + l4 * 8;
  f32x4 acc[4] = {};
  #pragma unroll
  for (int kb = 0; kb < 8; kb++) {
    bf16x8 a = *(const bf16x8*)(Ap + kb * 32);
    #pragma unroll
    for (int st = 0; st < 4; st++) {
      bf16x8 bfr = *(const bf16x8*)&hs[(st * 16 + l15) * 264 + kb * 32 + l4 * 8];
      acc[st] = __builtin_amdgcn_mfma_f32_16x16x32_bf16(a, bfr, acc[st], 0, 0, 0);
    }
  }
  float vals[4][4];
  #pragma unroll
  for (int j = 0; j < 4; j++) {
    int v = vt * 64 + wv * 16 + l4 * 4 + j;
    bool valid = v < V_;
    float bias = valid ? db2[v] : 0.f;
    size_t ob = ((size_t)n * V_ + v) * S_;
    #pragma unroll
    for (int st = 0; st < 4; st++) {
      float val = valid ? (acc[st][j] + bias) : -INFINITY;
      vals[st][j] = val;
      if (valid) out[ob + st * 16 + l15] = val;
    }
  }
  float lm[4];
  #pragma unroll
  for (int st = 0; st < 4; st++) {
    float m = fmaxf(fmaxf(vals[st][0], vals[st][1]), fmaxf(vals[st][2], vals[st][3]));
    m = fmaxf(m, __shfl_xor(m, 16, 64));
    m = fmaxf(m, __shfl_xor(m, 32, 64));
    lm[st] = m;
  }
  if (l4 == 0) {
    #pragma unroll
    for (int st = 0; st < 4; st++) redm[wv][st * 16 + l15] = lm[st];
  }
  __syncthreads();
  float bm[4], ls[4];
  #pragma unroll
  for (int st = 0; st < 4; st++) {
    int s = st * 16 + l15;
    bm[st] = fmaxf(fmaxf(redm[0][s], redm[1][s]), fmaxf(redm[2][s], redm[3][s]));
    float sum = 0.f;
    #pragma unroll
    for (int j = 0; j < 4; j++) sum += __expf(vals[st][j] - bm[st]);
    sum += __shfl_xor(sum, 16, 64);
    sum += __shfl_xor(sum, 32, 64);
    ls[st] = sum;
  }
  if (l4 == 0) {
    #pragma unroll
    for (int st = 0; st < 4; st++) reds[wv][st * 16 + l15] = ls[st];
  }
  __syncthreads();
  if (wv == 0 && l4 == 0) {
    #pragma unroll
    for (int st = 0; st < 4; st++) {
      int s = st * 16 + l15;
      float bs = reds[0][s] + reds[1][s] + reds[2][s] + reds[3][s];
      size_t pi = ((size_t)n * VT_ + vt) * S_ + s;
      pmax[pi] = bm[st];
      psum[pi] = bs;
    }
  }
}

// ---------------- loss finalize ----------------
__global__ __launch_bounds__(256) void k_lossf(
    const float* __restrict__ pmax, const float* __restrict__ psum,
    const float* __restrict__ out, const int* __restrict__ label,
    float* __restrict__ partial) {
  __shared__ float sm[256], ssum[256];
  int n = blockIdx.x, tid = threadIdx.x;
  int s = tid & 63, qq = tid >> 6;
  float m = -INFINITY, sum = 0.f;
  for (int vt = qq; vt < VT_; vt += 4) {
    size_t pi = ((size_t)n * VT_ + vt) * S_ + s;
    float m2 = pmax[pi], s2 = psum[pi];
    float nm = fmaxf(m, m2);
    sum = sum * __expf(m - nm) + s2 * __expf(m2 - nm);
    m = nm;
  }
  sm[tid] = m; ssum[tid] = sum;
  __syncthreads();
  if (qq == 0) {
    float M = sm[s], Sa = ssum[s];
    #pragma unroll
    for (int p = 1; p < 4; p++) {
      float m2 = sm[p * 64 + s], s2 = ssum[p * 64 + s];
      float nm = fmaxf(M, m2);
      Sa = Sa * __expf(M - nm) + s2 * __expf(m2 - nm);
      M = nm;
    }
    float lse = M + logf(Sa);
    int lab = label[n * S_ + s];
    float lx = out[((size_t)n * V_ + lab) * S_ + s];
    partial[n * S_ + s] = lse - lx;
  }
}

__global__ __launch_bounds__(256) void k_loss2(const float* __restrict__ partial,
                                               float* __restrict__ dst) {
  __shared__ float sbuf[4];
  int tid = threadIdx.x;
  float acc = 0.f;
  for (int i = tid; i < T_; i += 256) acc += partial[i];
  float tot = block_sum(acc, sbuf);
  if (tid == 0) dst[0] = tot / (float)T_;
}

extern "C" void kernel_launch(void* const* d_in, const int* in_sizes, int n_in,
                              void* d_out, int out_size, void* d_ws, size_t ws_size,
                              hipStream_t stream) {
  const int*   label = (const int*)d_in[0];
  const int*   mask  = (const int*)d_in[1];
  const float* emb   = (const float*)d_in[2];
  const float* pos   = (const float*)d_in[3];
  const float* emb_g = (const float*)d_in[4];
  const float* emb_b = (const float*)d_in[5];
  const float* Wq  = (const float*)d_in[6];
  const float* bq  = (const float*)d_in[7];
  const float* Wk  = (const float*)d_in[8];
  const float* bk  = (const float*)d_in[9];
  const float* Wv  = (const float*)d_in[10];
  const float* bv  = (const float*)d_in[11];
  const float* Wo  = (const float*)d_in[12];
  const float* bo  = (const float*)d_in[13];
  const float* n1g = (const float*)d_in[14];
  const float* n1b = (const float*)d_in[15];
  const float* W1  = (const float*)d_in[16];
  const float* b1  = (const float*)d_in[17];
  const float* W2  = (const float*)d_in[18];
  const float* b2  = (const float*)d_in[19];
  const float* n2g = (const float*)d_in[20];
  const float* n2b = (const float*)d_in[21];
  const float* dW1 = (const float*)d_in[22];
  const float* db1 = (const float*)d_in[23];
  const float* dng = (const float*)d_in[24];
  const float* dnb = (const float*)d_in[25];
  const float* dW2 = (const float*)d_in[26];
  const float* db2 = (const float*)d_in[27];
  float* out = (float*)d_out;
  (void)in_sizes; (void)n_in; (void)out_size; (void)ws_size;

  char* base = (char*)d_ws;
  size_t off = 0;
  auto alloc = [&](size_t bytes) {
    char* p = base + off;
    off += (bytes + 255) & ~(size_t)255;
    return p;
  };
  // span [x .. qkv] (37.8 MB) is reused for pmax/psum (34.1 MB) by k_vocab time
  float*    x    = (float*)alloc((size_t)T_ * E_ * 4);
  ushort_t* xb   = (ushort_t*)alloc((size_t)T_ * E_ * 2);
  float*    x1   = (float*)alloc((size_t)T_ * E_ * 4);
  ushort_t* x1b  = (ushort_t*)alloc((size_t)T_ * E_ * 2);
  ushort_t* qkv  = (ushort_t*)alloc((size_t)T_ * 768 * 2);
  ushort_t* obuf = (ushort_t*)alloc((size_t)T_ * E_ * 2);
  float*    ftmp = (float*)alloc((size_t)T_ * E_ * 4);
  ushort_t* wqkvT = (ushort_t*)alloc((size_t)L_ * 768 * E_ * 2);
  ushort_t* woT   = (ushort_t*)alloc((size_t)L_ * E_ * E_ * 2);
  ushort_t* w1T   = (ushort_t*)alloc((size_t)L_ * H_ * E_ * 2);
  ushort_t* w2T   = (ushort_t*)alloc((size_t)L_ * E_ * H_ * 2);
  ushort_t* dw1T  = (ushort_t*)alloc((size_t)E_ * E_ * 2);
  ushort_t* wt    = (ushort_t*)alloc((size_t)VPAD_ * E_ * 2);
  float*    bqkv  = (float*)alloc((size_t)L_ * 768 * 4);
  float*    partial = (float*)alloc((size_t)T_ * 4);
  ushort_t* ffh = qkv;        // alias: qkv dead after attn, ffh used later
  ushort_t* hbf = obuf;       // alias: obuf dead before decoder LN
  float* pmax = x;            // alias span (all dead by k_vocab)
  float* psum = pmax + (size_t)N_ * VT_ * S_;

  // ---- one-time weight prep ----
  k_bcat<<<L_, 256, 0, stream>>>(bq, bk, bv, bqkv);
  k_wt<<<dim3(8, 8, L_), 256, 0, stream>>>(Wq, wqkvT + 0 * 65536, E_, E_, 768 * E_);
  k_wt<<<dim3(8, 8, L_), 256, 0, stream>>>(Wk, wqkvT + 1 * 65536, E_, E_, 768 * E_);
  k_wt<<<dim3(8, 8, L_), 256, 0, stream>>>(Wv, wqkvT + 2 * 65536, E_, E_, 768 * E_);
  k_wt<<<dim3(8, 8, L_), 256, 0, stream>>>(Wo, woT, E_, E_, E_ * E_);
  k_wt<<<dim3(16, 8, L_), 256, 0, stream>>>(W1, w1T, E_, H_, H_ * E_);
  k_wt<<<dim3(8, 16, L_), 256, 0, stream>>>(W2, w2T, H_, E_, E_ * H_);
  k_wt<<<dim3(8, 8, 1), 256, 0, stream>>>(dW1, dw1T, E_, E_, E_ * E_);
  k_w2t<<<dim3(VPAD_ / 32, E_ / 32), 256, 0, stream>>>(dW2, wt);

  k_embed_ln<<<T_, 256, 0, stream>>>(label, mask, emb, pos, emb_g, emb_b, x, xb);

  for (int l = 0; l < L_; l++) {
    // fused QKV: [T][256] @ [768][256]^T -> qkv [T][768] bf16
    k_mm<E_, 1, 0><<<dim3(T_ / 64, 12), 256, 0, stream>>>(
        xb, wqkvT + (size_t)l * 768 * E_, bqkv + l * 768, qkv, 768);
    k_attn<<<N_ * NH_, 256, 0, stream>>>(qkv, obuf);
    k_mm<E_, 0, 0><<<dim3(T_ / 64, 4), 256, 0, stream>>>(
        obuf, woT + (size_t)l * E_ * E_, bo + l * E_, ftmp, E_);
    k_add_ln<<<T_, 256, 0, stream>>>(x, ftmp, n1g + l * E_, n1b + l * E_, x1, x1b);
    k_mm<E_, 1, 1><<<dim3(T_ / 64, 8), 256, 0, stream>>>(
        x1b, w1T + (size_t)l * H_ * E_, b1 + l * H_, ffh, H_);
    k_mm<H_, 0, 0><<<dim3(T_ / 64, 4), 256, 0, stream>>>(
        ffh, w2T + (size_t)l * E_ * H_, b2 + l * E_, ftmp, E_);
    k_add_ln<<<T_, 256, 0, stream>>>(x1, ftmp, n2g + l * E_, n2b + l * E_, x, xb);
  }

  // decoder head: gelu(x @ dW1 + db1) -> LN -> hbf (bf16)
  k_mm<E_, 0, 1><<<dim3(T_ / 64, 4), 256, 0, stream>>>(xb, dw1T, db1, ftmp, E_);
  k_add_ln<<<T_, 256, 0, stream>>>(ftmp, nullptr, dng, dnb, nullptr, hbf);

  // vocab projection + transposed store + fused softmax partials
  k_vocab<<<dim3(N_, VT_), 256, 0, stream>>>(hbf, wt, db2, out, pmax, psum);

  // loss
  k_lossf<<<N_, 256, 0, stream>>>(pmax, psum, out, label, partial);
  k_loss2<<<1, 256, 0, stream>>>(partial, out + (size_t)N_ * V_ * S_);
}

// Round 4
// 946.536 us; speedup vs baseline: 7.0169x; 1.3092x over previous
//
#include <hip/hip_runtime.h>
#include <hip/hip_bf16.h>

#define DEVFN static __device__ __forceinline__

constexpr int N_ = 128, S_ = 64, T_ = N_ * S_;
constexpr int E_ = 256, H_ = 512, NH_ = 8, DH_ = 32, L_ = 4;
constexpr int V_ = 33279, VPAD_ = 33280, NVT_ = VPAD_ / 128;  // 260 v-tiles of 128

typedef __attribute__((ext_vector_type(8))) short bf16x8;
typedef __attribute__((ext_vector_type(4))) float f32x4;
typedef unsigned short ushort_t;

DEVFN ushort_t f2bf(float f) {
  unsigned int u = __float_as_uint(f);
  unsigned int r = (u + 0x7fffu + ((u >> 16) & 1u)) >> 16;
  return (ushort_t)r;
}
DEVFN float bf2f(ushort_t u) { return __uint_as_float(((unsigned)u) << 16); }

DEVFN float geluf(float x) {
  return 0.5f * x * (1.f + erff(x * 0.70710678118654752440f));
}

DEVFN float wave_sum(float v) {
  #pragma unroll
  for (int off = 32; off >= 1; off >>= 1) v += __shfl_xor(v, off, 64);
  return v;
}

// ---------------- embedding + LN: one wave per token row ----------------
__global__ __launch_bounds__(256) void k_embed_ln(
    const int* __restrict__ label, const int* __restrict__ mask,
    const float* __restrict__ emb, const float* __restrict__ pos,
    const float* __restrict__ g, const float* __restrict__ b,
    float* __restrict__ x, ushort_t* __restrict__ xb) {
  int wv = threadIdx.x >> 6, lane = threadIdx.x & 63;
  int t = blockIdx.x * 4 + wv;
  int s = t & (S_ - 1);
  int id = (mask[t] == 1) ? V_ : label[t];
  int c = lane * 4;
  float4 v = *(const float4*)&emb[(size_t)id * E_ + c];
  float4 p = *(const float4*)&pos[s * E_ + c];
  v.x += p.x; v.y += p.y; v.z += p.z; v.w += p.w;
  float mean = wave_sum(v.x + v.y + v.z + v.w) * (1.f / E_);
  float4 d = {v.x - mean, v.y - mean, v.z - mean, v.w - mean};
  float var = wave_sum(d.x * d.x + d.y * d.y + d.z * d.z + d.w * d.w) * (1.f / E_);
  float rstd = 1.f / sqrtf(var + 1e-5f);
  float4 g4 = *(const float4*)&g[c];
  float4 b4 = *(const float4*)&b[c];
  float4 y = {d.x * rstd * g4.x + b4.x, d.y * rstd * g4.y + b4.y,
              d.z * rstd * g4.z + b4.z, d.w * rstd * g4.w + b4.w};
  *(float4*)&x[(size_t)t * E_ + c] = y;
  ushort4 yb = {f2bf(y.x), f2bf(y.y), f2bf(y.z), f2bf(y.w)};
  *(ushort4*)&xb[(size_t)t * E_ + c] = yb;
}

// ---------------- residual add + LN: one wave per row ----------------
__global__ __launch_bounds__(256) void k_add_ln(
    const float* __restrict__ a, const float* __restrict__ bsrc,
    const float* __restrict__ g, const float* __restrict__ bet,
    float* __restrict__ y, ushort_t* __restrict__ yb) {
  int wv = threadIdx.x >> 6, lane = threadIdx.x & 63;
  int t = blockIdx.x * 4 + wv;
  int c = lane * 4;
  float4 v = *(const float4*)&a[(size_t)t * E_ + c];
  if (bsrc) {
    float4 u = *(const float4*)&bsrc[(size_t)t * E_ + c];
    v.x += u.x; v.y += u.y; v.z += u.z; v.w += u.w;
  }
  float mean = wave_sum(v.x + v.y + v.z + v.w) * (1.f / E_);
  float4 d = {v.x - mean, v.y - mean, v.z - mean, v.w - mean};
  float var = wave_sum(d.x * d.x + d.y * d.y + d.z * d.z + d.w * d.w) * (1.f / E_);
  float rstd = 1.f / sqrtf(var + 1e-5f);
  float4 g4 = *(const float4*)&g[c];
  float4 b4 = *(const float4*)&bet[c];
  float4 o = {d.x * rstd * g4.x + b4.x, d.y * rstd * g4.y + b4.y,
              d.z * rstd * g4.z + b4.z, d.w * rstd * g4.w + b4.w};
  if (y) *(float4*)&y[(size_t)t * E_ + c] = o;
  if (yb) {
    ushort4 ob = {f2bf(o.x), f2bf(o.y), f2bf(o.z), f2bf(o.w)};
    *(ushort4*)&yb[(size_t)t * E_ + c] = ob;
  }
}

// ---------------- bias concat ----------------
__global__ __launch_bounds__(256) void k_bcat(
    const float* __restrict__ bq, const float* __restrict__ bk,
    const float* __restrict__ bv, float* __restrict__ bqkv) {
  int l = blockIdx.x, i = threadIdx.x;
  bqkv[l * 768 + i]       = bq[l * 256 + i];
  bqkv[l * 768 + 256 + i] = bk[l * 256 + i];
  bqkv[l * 768 + 512 + i] = bv[l * 256 + i];
}

// ---------------- transpose+convert: src[L][K][J] f32 -> dst[L][J][K] bf16 -------
__global__ __launch_bounds__(256) void k_wt(const float* __restrict__ src,
                                            ushort_t* __restrict__ dst,
                                            int K, int J, int dstLayerStride) {
  __shared__ float tile[32][33];
  int j0 = blockIdx.x * 32, k0 = blockIdx.y * 32, l = blockIdx.z;
  src += (size_t)l * K * J;
  dst += (size_t)l * dstLayerStride;
  int tx = threadIdx.x & 31, ty = threadIdx.x >> 5;
  #pragma unroll
  for (int rr = 0; rr < 4; rr++) {
    int kk = ty * 4 + rr;
    tile[kk][tx] = src[(size_t)(k0 + kk) * J + j0 + tx];
  }
  __syncthreads();
  #pragma unroll
  for (int rr = 0; rr < 4; rr++) {
    int jj = ty * 4 + rr;
    dst[(size_t)(j0 + jj) * K + k0 + tx] = f2bf(tile[tx][jj]);
  }
}

// ---------------- MFMA GEMM: C[T][Nout] = Xb[T][K] @ WT[Nout][K]^T + bias --------
template <int K, int OUT_BF16, int GELU_>
__global__ __launch_bounds__(256) void k_mm(
    const ushort_t* __restrict__ Xb, const ushort_t* __restrict__ WT,
    const float* __restrict__ bias, void* __restrict__ C, int Nout) {
  constexpr int STR = K + 8;
  __shared__ ushort_t xs[64 * STR];
  int tid = threadIdx.x, lane = tid & 63, wv = tid >> 6;
  int t0 = blockIdx.x * 64, j0 = blockIdx.y * 64;
  const ushort_t* xsrc = Xb + (size_t)t0 * K;
  for (int i = tid; i < 64 * (K / 8); i += 256) {
    int r = i / (K / 8), c = (i % (K / 8)) * 8;
    *(uint4*)&xs[r * STR + c] = *(const uint4*)&xsrc[(size_t)r * K + c];
  }
  __syncthreads();
  int l15 = lane & 15, l4 = lane >> 4;
  f32x4 acc[4] = {};
  const ushort_t* xrow = &xs[(wv * 16 + l15) * STR + l4 * 8];
  const ushort_t* wrow = WT + (size_t)j0 * K + l4 * 8;
  #pragma unroll
  for (int kb = 0; kb < K / 32; kb++) {
    bf16x8 a = *(const bf16x8*)(xrow + kb * 32);
    #pragma unroll
    for (int st = 0; st < 4; st++) {
      bf16x8 bfr = *(const bf16x8*)(wrow + (size_t)(st * 16 + l15) * K + kb * 32);
      acc[st] = __builtin_amdgcn_mfma_f32_16x16x32_bf16(a, bfr, acc[st], 0, 0, 0);
    }
  }
  #pragma unroll
  for (int st = 0; st < 4; st++) {
    int j = j0 + st * 16 + l15;
    float bv_ = bias[j];
    #pragma unroll
    for (int r = 0; r < 4; r++) {
      float val = acc[st][r] + bv_;
      if (GELU_) val = geluf(val);
      int t = t0 + wv * 16 + l4 * 4 + r;
      if (OUT_BF16)
        ((ushort_t*)C)[(size_t)t * Nout + j] = f2bf(val);
      else
        ((float*)C)[(size_t)t * Nout + j] = val;
    }
  }
}

// ---------------- MFMA attention: one block per (n, h) ----------------
__global__ __launch_bounds__(256) void k_attn(
    const ushort_t* __restrict__ qkv, ushort_t* __restrict__ o) {
  __shared__ __align__(16) ushort_t vt_[32 * 72];  // V^T [d][t]
  __shared__ __align__(16) ushort_t ps[64 * 72];   // P [s][t]
  int n = blockIdx.x >> 3, h = blockIdx.x & 7;
  int tid = threadIdx.x, lane = tid & 63, wv = tid >> 6;
  int l15 = lane & 15, l4 = lane >> 4;
  const ushort_t* qbase = qkv + (size_t)n * S_ * 768 + h * DH_;
  // stage V^T
  for (int i = tid; i < S_ * DH_; i += 256) {
    int t = i >> 5, d = i & 31;
    vt_[d * 72 + t] = qbase[(size_t)t * 768 + 512 + d];
  }
  // QK^T (K-dim = 32, one MFMA k-step)
  int srow = wv * 16 + l15;
  bf16x8 aq = *(const bf16x8*)&qbase[(size_t)srow * 768 + l4 * 8];
  f32x4 sc[4];
  #pragma unroll
  for (int st = 0; st < 4; st++) {
    bf16x8 bk_ = *(const bf16x8*)&qbase[(size_t)(st * 16 + l15) * 768 + 256 + l4 * 8];
    f32x4 z = {};
    sc[st] = __builtin_amdgcn_mfma_f32_16x16x32_bf16(aq, bk_, z, 0, 0, 0);
  }
  const float scale = 0.17677669529663687f;  // 1/sqrt(32)
  #pragma unroll
  for (int st = 0; st < 4; st++)
    #pragma unroll
    for (int r = 0; r < 4; r++) sc[st][r] *= scale;
  // softmax per s-row (s = wv*16 + l4*4 + r); t spread over (st, l15)
  #pragma unroll
  for (int r = 0; r < 4; r++) {
    float m = fmaxf(fmaxf(sc[0][r], sc[1][r]), fmaxf(sc[2][r], sc[3][r]));
    m = fmaxf(m, __shfl_xor(m, 1, 64));
    m = fmaxf(m, __shfl_xor(m, 2, 64));
    m = fmaxf(m, __shfl_xor(m, 4, 64));
    m = fmaxf(m, __shfl_xor(m, 8, 64));
    float p0 = __expf(sc[0][r] - m), p1 = __expf(sc[1][r] - m);
    float p2 = __expf(sc[2][r] - m), p3 = __expf(sc[3][r] - m);
    float sum = p0 + p1 + p2 + p3;
    sum += __shfl_xor(sum, 1, 64);
    sum += __shfl_xor(sum, 2, 64);
    sum += __shfl_xor(sum, 4, 64);
    sum += __shfl_xor(sum, 8, 64);
    float inv = 1.f / sum;
    int prow = (wv * 16 + l4 * 4 + r) * 72;
    ps[prow + 0 * 16 + l15] = f2bf(p0 * inv);
    ps[prow + 1 * 16 + l15] = f2bf(p1 * inv);
    ps[prow + 2 * 16 + l15] = f2bf(p2 * inv);
    ps[prow + 3 * 16 + l15] = f2bf(p3 * inv);
  }
  __syncthreads();
  // PV: O[s][d] = P[s][t] @ V[t][d], via A=P rows, B=V^T rows
  f32x4 oc[2] = {};
  #pragma unroll
  for (int kb = 0; kb < 2; kb++) {
    bf16x8 ap = *(const bf16x8*)&ps[srow * 72 + kb * 32 + l4 * 8];
    #pragma unroll
    for (int st2 = 0; st2 < 2; st2++) {
      bf16x8 bv_ = *(const bf16x8*)&vt_[(st2 * 16 + l15) * 72 + kb * 32 + l4 * 8];
      oc[st2] = __builtin_amdgcn_mfma_f32_16x16x32_bf16(ap, bv_, oc[st2], 0, 0, 0);
    }
  }
  ushort_t* ob = o + (size_t)n * S_ * E_ + h * DH_;
  #pragma unroll
  for (int st2 = 0; st2 < 2; st2++)
    #pragma unroll
    for (int r = 0; r < 4; r++)
      ob[(size_t)(wv * 16 + l4 * 4 + r) * E_ + st2 * 16 + l15] = f2bf(oc[st2][r]);
}

// ---------------- dW2 [E][V] f32 -> wt [VPAD][E] bf16 ----------------
__global__ __launch_bounds__(256) void k_w2t(const float* __restrict__ w,
                                             ushort_t* __restrict__ wt) {
  __shared__ float tile[32 * 33];
  int tx = threadIdx.x & 31, ty = threadIdx.x >> 5;
  int v0 = blockIdx.x * 32, k0 = blockIdx.y * 32;
  #pragma unroll
  for (int rr = 0; rr < 4; rr++) {
    int kk = ty * 4 + rr;
    int vv = v0 + tx;
    tile[kk * 33 + tx] = (vv < V_) ? w[(size_t)(k0 + kk) * V_ + vv] : 0.f;
  }
  __syncthreads();
  #pragma unroll
  for (int rr = 0; rr < 4; rr++) {
    int vv = ty * 4 + rr;
    wt[(size_t)(v0 + vv) * E_ + k0 + tx] = f2bf(tile[tx * 33 + vv]);
  }
}

// ---------------- vocab GEMM (128v x 64s tile) + fused softmax partials ----------
__global__ __launch_bounds__(256) void k_vocab(
    const ushort_t* __restrict__ hbf, const ushort_t* __restrict__ wt,
    const float* __restrict__ db2, float* __restrict__ out,
    float* __restrict__ pmax, float* __restrict__ psum) {
  __shared__ ushort_t hs[64 * 264];
  __shared__ float redm[4][64];
  __shared__ float reds[4][64];
  int n = blockIdx.x, vt = blockIdx.y;
  int tid = threadIdx.x, lane = tid & 63, wv = tid >> 6;
  const ushort_t* hsrc = hbf + (size_t)n * S_ * E_;
  for (int i = tid; i < (S_ * E_) / 8; i += 256) {
    int s = i >> 5, kc = (i & 31) * 8;
    *(uint4*)&hs[s * 264 + kc] = *(const uint4*)&hsrc[s * E_ + kc];
  }
  __syncthreads();
  int l15 = lane & 15, l4 = lane >> 4;
  const ushort_t* Ap0 = wt + (size_t)(vt * 128 + wv * 16 + l15) * E_ + l4 * 8;
  const ushort_t* Ap1 = Ap0 + (size_t)64 * E_;
  f32x4 acc[2][4] = {};
  #pragma unroll
  for (int kb = 0; kb < 8; kb++) {
    bf16x8 a0 = *(const bf16x8*)(Ap0 + kb * 32);
    bf16x8 a1 = *(const bf16x8*)(Ap1 + kb * 32);
    #pragma unroll
    for (int st = 0; st < 4; st++) {
      bf16x8 bfr = *(const bf16x8*)&hs[(st * 16 + l15) * 264 + kb * 32 + l4 * 8];
      acc[0][st] = __builtin_amdgcn_mfma_f32_16x16x32_bf16(a0, bfr, acc[0][st], 0, 0, 0);
      acc[1][st] = __builtin_amdgcn_mfma_f32_16x16x32_bf16(a1, bfr, acc[1][st], 0, 0, 0);
    }
  }
  // vals[mt][st][j]: logit for v = vt*128 + wv*16 + mt*64 + l4*4 + j, s = st*16+l15
  float vals[2][4][4];
  #pragma unroll
  for (int mt = 0; mt < 2; mt++) {
    #pragma unroll
    for (int j = 0; j < 4; j++) {
      int v = vt * 128 + wv * 16 + mt * 64 + l4 * 4 + j;
      bool valid = v < V_;
      float bias = valid ? db2[v] : 0.f;
      size_t ob = ((size_t)n * V_ + v) * S_;
      #pragma unroll
      for (int st = 0; st < 4; st++) {
        float val = valid ? (acc[mt][st][j] + bias) : -INFINITY;
        vals[mt][st][j] = val;
        if (valid) __builtin_nontemporal_store(val, &out[ob + st * 16 + l15]);
      }
    }
  }
  // per-s (max, sumexp) over this block's 128 v
  float lm[4];
  #pragma unroll
  for (int st = 0; st < 4; st++) {
    float m = -INFINITY;
    #pragma unroll
    for (int mt = 0; mt < 2; mt++)
      #pragma unroll
      for (int j = 0; j < 4; j++) m = fmaxf(m, vals[mt][st][j]);
    m = fmaxf(m, __shfl_xor(m, 16, 64));
    m = fmaxf(m, __shfl_xor(m, 32, 64));
    lm[st] = m;
  }
  if (l4 == 0) {
    #pragma unroll
    for (int st = 0; st < 4; st++) redm[wv][st * 16 + l15] = lm[st];
  }
  __syncthreads();
  float bm[4], ls[4];
  #pragma unroll
  for (int st = 0; st < 4; st++) {
    int s = st * 16 + l15;
    bm[st] = fmaxf(fmaxf(redm[0][s], redm[1][s]), fmaxf(redm[2][s], redm[3][s]));
    float sum = 0.f;
    #pragma unroll
    for (int mt = 0; mt < 2; mt++)
      #pragma unroll
      for (int j = 0; j < 4; j++) sum += __expf(vals[mt][st][j] - bm[st]);
    sum += __shfl_xor(sum, 16, 64);
    sum += __shfl_xor(sum, 32, 64);
    ls[st] = sum;
  }
  if (l4 == 0) {
    #pragma unroll
    for (int st = 0; st < 4; st++) reds[wv][st * 16 + l15] = ls[st];
  }
  __syncthreads();
  if (wv == 0 && l4 == 0) {
    #pragma unroll
    for (int st = 0; st < 4; st++) {
      int s = st * 16 + l15;
      float bs = reds[0][s] + reds[1][s] + reds[2][s] + reds[3][s];
      size_t pi = ((size_t)n * NVT_ + vt) * S_ + s;
      pmax[pi] = bm[st];
      psum[pi] = bs;
    }
  }
}

// ---------------- loss finalize (512 threads) ----------------
__global__ __launch_bounds__(512) void k_lossf(
    const float* __restrict__ pmax, const float* __restrict__ psum,
    const float* __restrict__ out, const int* __restrict__ label,
    float* __restrict__ partial) {
  __shared__ float sm[512], ssum[512];
  int n = blockIdx.x, tid = threadIdx.x;
  int s = tid & 63, qq = tid >> 6;  // qq in [0,8)
  float m = -INFINITY, sum = 0.f;
  for (int vt = qq; vt < NVT_; vt += 8) {
    size_t pi = ((size_t)n * NVT_ + vt) * S_ + s;
    float m2 = pmax[pi], s2 = psum[pi];
    float nm = fmaxf(m, m2);
    sum = sum * __expf(m - nm) + s2 * __expf(m2 - nm);
    m = nm;
  }
  sm[tid] = m; ssum[tid] = sum;
  __syncthreads();
  if (qq == 0) {
    float M = sm[s], Sa = ssum[s];
    #pragma unroll
    for (int p = 1; p < 8; p++) {
      float m2 = sm[p * 64 + s], s2 = ssum[p * 64 + s];
      float nm = fmaxf(M, m2);
      Sa = Sa * __expf(M - nm) + s2 * __expf(m2 - nm);
      M = nm;
    }
    float lse = M + logf(Sa);
    int lab = label[n * S_ + s];
    float lx = out[((size_t)n * V_ + lab) * S_ + s];
    partial[n * S_ + s] = lse - lx;
  }
}

__global__ __launch_bounds__(256) void k_loss2(const float* __restrict__ partial,
                                               float* __restrict__ dst) {
  __shared__ float sbuf[4];
  int tid = threadIdx.x;
  float acc = 0.f;
  for (int i = tid; i < T_; i += 256) acc += partial[i];
  #pragma unroll
  for (int off = 32; off >= 1; off >>= 1) acc += __shfl_xor(acc, off, 64);
  int lane = tid & 63, wid = tid >> 6;
  if (lane == 0) sbuf[wid] = acc;
  __syncthreads();
  if (tid == 0) dst[0] = (sbuf[0] + sbuf[1] + sbuf[2] + sbuf[3]) / (float)T_;
}

extern "C" void kernel_launch(void* const* d_in, const int* in_sizes, int n_in,
                              void* d_out, int out_size, void* d_ws, size_t ws_size,
                              hipStream_t stream) {
  const int*   label = (const int*)d_in[0];
  const int*   mask  = (const int*)d_in[1];
  const float* emb   = (const float*)d_in[2];
  const float* pos   = (const float*)d_in[3];
  const float* emb_g = (const float*)d_in[4];
  const float* emb_b = (const float*)d_in[5];
  const float* Wq  = (const float*)d_in[6];
  const float* bq  = (const float*)d_in[7];
  const float* Wk  = (const float*)d_in[8];
  const float* bk  = (const float*)d_in[9];
  const float* Wv  = (const float*)d_in[10];
  const float* bv  = (const float*)d_in[11];
  const float* Wo  = (const float*)d_in[12];
  const float* bo  = (const float*)d_in[13];
  const float* n1g = (const float*)d_in[14];
  const float* n1b = (const float*)d_in[15];
  const float* W1  = (const float*)d_in[16];
  const float* b1  = (const float*)d_in[17];
  const float* W2  = (const float*)d_in[18];
  const float* b2  = (const float*)d_in[19];
  const float* n2g = (const float*)d_in[20];
  const float* n2b = (const float*)d_in[21];
  const float* dW1 = (const float*)d_in[22];
  const float* db1 = (const float*)d_in[23];
  const float* dng = (const float*)d_in[24];
  const float* dnb = (const float*)d_in[25];
  const float* dW2 = (const float*)d_in[26];
  const float* db2 = (const float*)d_in[27];
  float* out = (float*)d_out;
  (void)in_sizes; (void)n_in; (void)out_size; (void)ws_size;

  char* base = (char*)d_ws;
  size_t off = 0;
  auto alloc = [&](size_t bytes) {
    char* p = base + off;
    off += (bytes + 255) & ~(size_t)255;
    return p;
  };
  float*    x    = (float*)alloc((size_t)T_ * E_ * 4);
  ushort_t* xb   = (ushort_t*)alloc((size_t)T_ * E_ * 2);
  float*    x1   = (float*)alloc((size_t)T_ * E_ * 4);
  ushort_t* x1b  = (ushort_t*)alloc((size_t)T_ * E_ * 2);
  ushort_t* qkv  = (ushort_t*)alloc((size_t)T_ * 768 * 2);
  ushort_t* obuf = (ushort_t*)alloc((size_t)T_ * E_ * 2);
  float*    ftmp = (float*)alloc((size_t)T_ * E_ * 4);
  ushort_t* wqkvT = (ushort_t*)alloc((size_t)L_ * 768 * E_ * 2);
  ushort_t* woT   = (ushort_t*)alloc((size_t)L_ * E_ * E_ * 2);
  ushort_t* w1T   = (ushort_t*)alloc((size_t)L_ * H_ * E_ * 2);
  ushort_t* w2T   = (ushort_t*)alloc((size_t)L_ * E_ * H_ * 2);
  ushort_t* dw1T  = (ushort_t*)alloc((size_t)E_ * E_ * 2);
  ushort_t* wt    = (ushort_t*)alloc((size_t)VPAD_ * E_ * 2);
  float*    bqkv  = (float*)alloc((size_t)L_ * 768 * 4);
  float*    partial = (float*)alloc((size_t)T_ * 4);
  ushort_t* ffh = qkv;        // alias: qkv dead after attn
  ushort_t* hbf = obuf;       // alias: obuf dead before decoder LN
  float* pmax = x;            // alias: x.. span dead by k_vocab (17 MB needed)
  float* psum = pmax + (size_t)N_ * NVT_ * S_;

  // ---- one-time weight prep ----
  k_bcat<<<L_, 256, 0, stream>>>(bq, bk, bv, bqkv);
  k_wt<<<dim3(8, 8, L_), 256, 0, stream>>>(Wq, wqkvT + 0 * 65536, E_, E_, 768 * E_);
  k_wt<<<dim3(8, 8, L_), 256, 0, stream>>>(Wk, wqkvT + 1 * 65536, E_, E_, 768 * E_);
  k_wt<<<dim3(8, 8, L_), 256, 0, stream>>>(Wv, wqkvT + 2 * 65536, E_, E_, 768 * E_);
  k_wt<<<dim3(8, 8, L_), 256, 0, stream>>>(Wo, woT, E_, E_, E_ * E_);
  k_wt<<<dim3(16, 8, L_), 256, 0, stream>>>(W1, w1T, E_, H_, H_ * E_);
  k_wt<<<dim3(8, 16, L_), 256, 0, stream>>>(W2, w2T, H_, E_, E_ * H_);
  k_wt<<<dim3(8, 8, 1), 256, 0, stream>>>(dW1, dw1T, E_, E_, E_ * E_);
  k_w2t<<<dim3(VPAD_ / 32, E_ / 32), 256, 0, stream>>>(dW2, wt);

  k_embed_ln<<<T_ / 4, 256, 0, stream>>>(label, mask, emb, pos, emb_g, emb_b, x, xb);

  for (int l = 0; l < L_; l++) {
    k_mm<E_, 1, 0><<<dim3(T_ / 64, 12), 256, 0, stream>>>(
        xb, wqkvT + (size_t)l * 768 * E_, bqkv + l * 768, qkv, 768);
    k_attn<<<N_ * NH_, 256, 0, stream>>>(qkv, obuf);
    k_mm<E_, 0, 0><<<dim3(T_ / 64, 4), 256, 0, stream>>>(
        obuf, woT + (size_t)l * E_ * E_, bo + l * E_, ftmp, E_);
    k_add_ln<<<T_ / 4, 256, 0, stream>>>(x, ftmp, n1g + l * E_, n1b + l * E_, x1, x1b);
    k_mm<E_, 1, 1><<<dim3(T_ / 64, 8), 256, 0, stream>>>(
        x1b, w1T + (size_t)l * H_ * E_, b1 + l * H_, ffh, H_);
    k_mm<H_, 0, 0><<<dim3(T_ / 64, 4), 256, 0, stream>>>(
        ffh, w2T + (size_t)l * E_ * H_, b2 + l * E_, ftmp, E_);
    k_add_ln<<<T_ / 4, 256, 0, stream>>>(x1, ftmp, n2g + l * E_, n2b + l * E_, x, xb);
  }

  // decoder head
  k_mm<E_, 0, 1><<<dim3(T_ / 64, 4), 256, 0, stream>>>(xb, dw1T, db1, ftmp, E_);
  k_add_ln<<<T_ / 4, 256, 0, stream>>>(ftmp, nullptr, dng, dnb, nullptr, hbf);

  // vocab projection + transposed store + fused softmax partials
  k_vocab<<<dim3(N_, NVT_), 256, 0, stream>>>(hbf, wt, db2, out, pmax, psum);

  // loss
  k_lossf<<<N_, 512, 0, stream>>>(pmax, psum, out, label, partial);
  k_loss2<<<1, 256, 0, stream>>>(partial, out + (size_t)N_ * V_ * S_);
}